// Round 3
// baseline (630.840 us; speedup 1.0000x reference)
//
#include <hip/hip_runtime.h>

#define NSTEPS 128
#define MIN_NEAR 0.2f
#define T_THRESH 1e-4f

// 8 lanes per ray, 16 steps per lane; 8 rays per wave, 32 rays per 256-thread block.
// Inputs/outputs are float32 per the reference (jax default dtype).
__global__ __launch_bounds__(256) void nerf_composite(
    const float* __restrict__ rays_o,
    const float* __restrict__ rays_d,
    const float* __restrict__ sigmas,
    const float* __restrict__ rgbs,
    float* __restrict__ out,   // [3N image | N depth | N depth_norm]
    int N)
{
    const int wave = threadIdx.x >> 6;            // 0..3
    const int lane = threadIdx.x & 63;
    const int seg  = lane >> 3;                   // 0..7  (ray within wave)
    const int li   = lane & 7;                    // 0..7  (lane within ray)
    const int ray  = (blockIdx.x * 4 + wave) * 8 + seg;
    if (ray >= N) return;

    // ---- ray origin / direction (8 lanes/segment hit same address -> broadcast) ----
    const float o0 = rays_o[3 * ray + 0];
    const float o1 = rays_o[3 * ray + 1];
    const float o2 = rays_o[3 * ray + 2];
    const float d0 = rays_d[3 * ray + 0];
    const float d1 = rays_d[3 * ray + 1];
    const float d2 = rays_d[3 * ray + 2];

    // ---- issue bulk loads early: 4 float4 sigma + 12 float4 rgb per lane ----
    const float4* sp = (const float4*)(sigmas + (size_t)ray * NSTEPS);   // 128 floats/ray
    float4 sv[4];
    #pragma unroll
    for (int j = 0; j < 4; ++j) sv[j] = sp[li * 4 + j];                  // steps li*16..li*16+15

    const float4* rp = (const float4*)(rgbs + (size_t)ray * NSTEPS * 3); // 384 floats/ray
    float col[48];
    #pragma unroll
    for (int j = 0; j < 12; ++j) {
        float4 c = rp[li * 12 + j];
        col[4 * j + 0] = c.x; col[4 * j + 1] = c.y;
        col[4 * j + 2] = c.z; col[4 * j + 3] = c.w;
    }

    // ---- slab test against [-1, 1]^3 (matches reference exactly) ----
    float tmin = -3.0e38f, tmax = 3.0e38f;
    {
        float dc, ta, tb;
        dc = (fabsf(d0) < 1e-8f) ? 1e-8f : d0;
        ta = (-1.0f - o0) / dc;  tb = (1.0f - o0) / dc;
        tmin = fmaxf(tmin, fminf(ta, tb));  tmax = fminf(tmax, fmaxf(ta, tb));
        dc = (fabsf(d1) < 1e-8f) ? 1e-8f : d1;
        ta = (-1.0f - o1) / dc;  tb = (1.0f - o1) / dc;
        tmin = fmaxf(tmin, fminf(ta, tb));  tmax = fminf(tmax, fmaxf(ta, tb));
        dc = (fabsf(d2) < 1e-8f) ? 1e-8f : d2;
        ta = (-1.0f - o2) / dc;  tb = (1.0f - o2) / dc;
        tmin = fmaxf(tmin, fminf(ta, tb));  tmax = fminf(tmax, fmaxf(ta, tb));
    }
    const float nearv = fmaxf(tmin, MIN_NEAR);
    const float farv  = fmaxf(tmax, nearv + 1e-4f);
    const float delta = (farv - nearv) * (1.0f / (float)NSTEPS);

    // ---- pass 1: e_k = exp(-sigma_k * delta); lane-local product of f_k = e_k + 1e-10 ----
    float e[16];
    #pragma unroll
    for (int j = 0; j < 4; ++j) {
        e[4 * j + 0] = __expf(-sv[j].x * delta);
        e[4 * j + 1] = __expf(-sv[j].y * delta);
        e[4 * j + 2] = __expf(-sv[j].z * delta);
        e[4 * j + 3] = __expf(-sv[j].w * delta);
    }
    float P = 1.0f;
    #pragma unroll
    for (int k = 0; k < 16; ++k) P *= e[k] + 1e-10f;

    // ---- segmented (width=8) inclusive product-scan, then exclusive shift ----
    float scan = P;
    #pragma unroll
    for (int off = 1; off < 8; off <<= 1) {
        float v = __shfl_up(scan, off, 8);
        if (li >= off) scan *= v;
    }
    float T = __shfl_up(scan, 1, 8);   // exclusive prefix across lanes of the segment
    if (li == 0) T = 1.0f;

    // ---- pass 2: serial composite over this lane's 16 steps ----
    const float tbase = nearv + ((float)(li * 16) + 0.5f) * delta;
    float ws = 0.0f, dp = 0.0f, ir = 0.0f, ig = 0.0f, ib = 0.0f;
    #pragma unroll
    for (int k = 0; k < 16; ++k) {
        const float a = 1.0f - e[k];
        const float w = (T > T_THRESH) ? a * T : 0.0f;
        const float t = tbase + (float)k * delta;
        ws += w;
        dp += w * t;
        ir += w * col[3 * k + 0];
        ig += w * col[3 * k + 1];
        ib += w * col[3 * k + 2];
        T *= e[k] + 1e-10f;
    }

    // ---- segmented butterfly reduce (width=8) of 5 accumulators ----
    #pragma unroll
    for (int off = 4; off > 0; off >>= 1) {
        ws += __shfl_xor(ws, off, 8);
        dp += __shfl_xor(dp, off, 8);
        ir += __shfl_xor(ir, off, 8);
        ig += __shfl_xor(ig, off, 8);
        ib += __shfl_xor(ib, off, 8);
    }

    if (li == 0) {
        const float bg = 1.0f - ws;   // BG_COLOR = 1.0
        out[3 * ray + 0] = ir + bg;
        out[3 * ray + 1] = ig + bg;
        out[3 * ray + 2] = ib + bg;
        out[3 * N + ray] = dp;
        out[4 * N + ray] = fmaxf(dp - nearv, 0.0f) / (farv - nearv);
    }
}

extern "C" void kernel_launch(void* const* d_in, const int* in_sizes, int n_in,
                              void* d_out, int out_size, void* d_ws, size_t ws_size,
                              hipStream_t stream) {
    const float* rays_o = (const float*)d_in[0];
    const float* rays_d = (const float*)d_in[1];
    const float* sigmas = (const float*)d_in[2];
    const float* rgbs   = (const float*)d_in[3];
    float* out = (float*)d_out;

    const int N = in_sizes[0] / 3;           // 262144 rays
    const int raysPerBlock = 32;             // 256 threads = 4 waves x 8 rays
    const int grid = (N + raysPerBlock - 1) / raysPerBlock;
    nerf_composite<<<grid, 256, 0, stream>>>(rays_o, rays_d, sigmas, rgbs, out, N);
}